// Round 1
// baseline (124.843 us; speedup 1.0000x reference)
//
#include <hip/hip_runtime.h>

#define BATCH  4096
#define LEN    8192
#define NB     12
#define ALPHA  0.9f
#define TPB    256
#define EPT    32   // elements per thread; TPB*EPT == LEN

__device__ __forceinline__ float elu_f(float t) {
    // elu(t) = t > 0 ? t : exp(t) - 1
    return t > 0.0f ? t : __expf(t) - 1.0f;
}

__global__ __launch_bounds__(TPB, 4)
void resconv1d_kernel(const float* __restrict__ x_in,
                      const float* __restrict__ w1,
                      const float* __restrict__ b1,
                      const float* __restrict__ w2,
                      const float* __restrict__ b2,
                      float* __restrict__ out)
{
    // halo exchange buffers (double-buffered -> one barrier per block-iter)
    __shared__ float s_first[2][TPB];
    __shared__ float s_last [2][TPB];
    __shared__ float s_w[NB * 6];

    const int t   = threadIdx.x;
    const int row = blockIdx.x;

    // ---- load this thread's 32 contiguous elements (8x float4) ----
    const float* xp = x_in + (size_t)row * LEN + (size_t)t * EPT;
    float x[EPT];
    #pragma unroll
    for (int k = 0; k < EPT / 4; ++k) {
        float4 v = reinterpret_cast<const float4*>(xp)[k];
        x[4*k+0] = v.x; x[4*k+1] = v.y; x[4*k+2] = v.z; x[4*k+3] = v.w;
    }

    // ---- stage the 12 blocks' weights in LDS once ----
    if (t < NB) {
        s_w[t*6+0] = w1[2*t];
        s_w[t*6+1] = w1[2*t+1];
        s_w[t*6+2] = b1[t];
        s_w[t*6+3] = w2[2*t];
        s_w[t*6+4] = w2[2*t+1];
        s_w[t*6+5] = b2[t];
    }

    #pragma unroll 1
    for (int it = 0; it < NB; ++it) {
        const int buf = it & 1;
        s_first[buf][t] = x[0];
        s_last [buf][t] = x[EPT-1];
        __syncthreads();   // also covers the one-time s_w writes (it==0)

        const float w10 = s_w[it*6+0];
        const float w11 = s_w[it*6+1];
        const float bb1 = s_w[it*6+2];
        const float w20 = s_w[it*6+3];
        const float w21 = s_w[it*6+4];
        const float bb2 = s_w[it*6+5];

        // halo: x[-1] of my chunk (left neighbor's last) and x[EPT] (right's first)
        float xl = s_last [buf][t > 0 ? t - 1 : 0];
        float xr = s_first[buf][t < TPB-1 ? t + 1 : TPB-1];
        xl = (t == 0)       ? 0.0f : xl;   // row left edge: x[-1] = 0
        xr = (t == TPB - 1) ? 0.0f : xr;   // row right edge: x[L]  = 0

        // a[i] = w10*x[i-1] + w11*x[i] + b1   (pre-activation of conv1)
        float a0 = fmaf(w10, xl, fmaf(w11, x[0], bb1));
        float e0 = elu_f(a0);
        #pragma unroll
        for (int j = 0; j < EPT; ++j) {
            const float xn = (j < EPT - 1) ? x[j+1] : xr;
            const float a1 = fmaf(w10, x[j], fmaf(w11, xn, bb1));  // a[i+1]
            const float e1 = elu_f(a1);
            // out[i] = x[i] + alpha*(w20*e(a[i]) + w21*e(a[i+1]) + b2)
            x[j] = fmaf(ALPHA, fmaf(w20, e0, fmaf(w21, e1, bb2)), x[j]);
            e0 = e1;
        }
        // next iteration writes the other halo buffer, so a single barrier
        // per iteration is race-free.
    }

    // ---- store ----
    float* op = out + (size_t)row * LEN + (size_t)t * EPT;
    #pragma unroll
    for (int k = 0; k < EPT / 4; ++k) {
        float4 v = make_float4(x[4*k+0], x[4*k+1], x[4*k+2], x[4*k+3]);
        reinterpret_cast<float4*>(op)[k] = v;
    }
}

extern "C" void kernel_launch(void* const* d_in, const int* in_sizes, int n_in,
                              void* d_out, int out_size, void* d_ws, size_t ws_size,
                              hipStream_t stream) {
    const float* x  = (const float*)d_in[0];
    const float* w1 = (const float*)d_in[1];
    const float* b1 = (const float*)d_in[2];
    const float* w2 = (const float*)d_in[3];
    const float* b2 = (const float*)d_in[4];
    float* out = (float*)d_out;

    resconv1d_kernel<<<dim3(BATCH), dim3(TPB), 0, stream>>>(x, w1, b1, w2, b2, out);
}

// Round 2
// 106.406 us; speedup vs baseline: 1.1733x; 1.1733x over previous
//
#include <hip/hip_runtime.h>

#define BATCH  4096
#define LEN    8192
#define NB     12
#define TPB    256
#define EPT    32   // elements per thread; TPB*EPT == LEN

__global__ __launch_bounds__(TPB, 8)
void resconv1d_kernel(const float* __restrict__ x_in,
                      const float* __restrict__ w1,
                      const float* __restrict__ b1,
                      const float* __restrict__ w2,
                      const float* __restrict__ b2,
                      float* __restrict__ out)
{
    // halo exchange buffers (double-buffered -> one barrier per block-iter)
    __shared__ float s_first[2][TPB];
    __shared__ float s_last [2][TPB];
    __shared__ float s_w[NB][6];   // prescaled per-block weights

    const int t   = threadIdx.x;
    const int row = blockIdx.x;

    // ---- load this thread's 32 contiguous elements (8x float4) ----
    const float* xp = x_in + (size_t)row * LEN + (size_t)t * EPT;
    float x[EPT];
    #pragma unroll
    for (int k = 0; k < EPT / 4; ++k) {
        float4 v = reinterpret_cast<const float4*>(xp)[k];
        x[4*k+0] = v.x; x[4*k+1] = v.y; x[4*k+2] = v.z; x[4*k+3] = v.w;
    }

    // ---- stage prescaled weights in LDS once ----
    // as = (w10*xl + w11*xc + b1) * log2e  -> prescale w1,b1 by log2e.
    // conv2 with shifted elu ep = elu+1:
    //   out = x + a*b2 + a*w20*(ep0-1) + a*w21*(ep1-1)
    //       = (x + cc) + aw20*ep0 + aw21*ep1,  cc = a*b2 - aw20 - aw21
    if (t < NB) {
        const float LOG2E = 1.4426950408889634f;
        const float aw20 = 0.9f * w2[2*t];
        const float aw21 = 0.9f * w2[2*t+1];
        s_w[t][0] = w1[2*t]   * LOG2E;
        s_w[t][1] = w1[2*t+1] * LOG2E;
        s_w[t][2] = b1[t]     * LOG2E;
        s_w[t][3] = aw20;
        s_w[t][4] = aw21;
        s_w[t][5] = 0.9f * b2[t] - aw20 - aw21;
    }

    // loop-invariant halo addressing / edge masks (hoisted selects)
    const int   idxl  = (t > 0)       ? t - 1 : 0;
    const int   idxr  = (t < TPB - 1) ? t + 1 : TPB - 1;
    const float maskl = (t > 0)       ? 1.0f : 0.0f;   // row edge: x[-1] = 0
    const float maskr = (t < TPB - 1) ? 1.0f : 0.0f;   // row edge: x[L]  = 0

    #pragma unroll 1
    for (int it = 0; it < NB; ++it) {
        const int buf = it & 1;
        s_first[buf][t] = x[0];
        s_last [buf][t] = x[EPT-1];
        __syncthreads();   // also covers the one-time s_w writes (it==0)

        const float w10s = s_w[it][0];
        const float w11s = s_w[it][1];
        const float b1s  = s_w[it][2];
        const float aw20 = s_w[it][3];
        const float aw21 = s_w[it][4];
        const float cc   = s_w[it][5];

        const float xl = s_last [buf][idxl] * maskl;
        const float xr = s_first[buf][idxr] * maskr;

        const float LN2 = 0.6931471805599453f;
        // shifted elu: ep(a) = elu(a)+1 = exp2(min(as,0)) + LN2*max(as,0)
        float as0 = fmaf(w10s, xl, fmaf(w11s, x[0], b1s));
        float ep0 = fmaf(fmaxf(as0, 0.0f), LN2,
                         __builtin_amdgcn_exp2f(fminf(as0, 0.0f)));
        #pragma unroll
        for (int j = 0; j < EPT; ++j) {
            const float xn  = (j < EPT - 1) ? x[j+1] : xr;   // static select
            const float as1 = fmaf(w10s, x[j], fmaf(w11s, xn, b1s));
            const float ep1 = fmaf(fmaxf(as1, 0.0f), LN2,
                                   __builtin_amdgcn_exp2f(fminf(as1, 0.0f)));
            x[j] = fmaf(aw20, ep0, fmaf(aw21, ep1, x[j] + cc));
            ep0 = ep1;
        }
        // next iteration writes the other halo buffer; barrier_{it+1} sits
        // between this iter's reads of buf and iter it+2's writes of buf.
    }

    // ---- store ----
    float* op = out + (size_t)row * LEN + (size_t)t * EPT;
    #pragma unroll
    for (int k = 0; k < EPT / 4; ++k) {
        reinterpret_cast<float4*>(op)[k] =
            make_float4(x[4*k+0], x[4*k+1], x[4*k+2], x[4*k+3]);
    }
}

extern "C" void kernel_launch(void* const* d_in, const int* in_sizes, int n_in,
                              void* d_out, int out_size, void* d_ws, size_t ws_size,
                              hipStream_t stream) {
    const float* x  = (const float*)d_in[0];
    const float* w1 = (const float*)d_in[1];
    const float* b1 = (const float*)d_in[2];
    const float* w2 = (const float*)d_in[3];
    const float* b2 = (const float*)d_in[4];
    float* out = (float*)d_out;

    resconv1d_kernel<<<dim3(BATCH), dim3(TPB), 0, stream>>>(x, w1, b1, w2, b2, out);
}

// Round 3
// 103.569 us; speedup vs baseline: 1.2054x; 1.0274x over previous
//
#include <hip/hip_runtime.h>

#define BATCH  4096
#define LEN    8192
#define NB     12
#define TPB    256
#define EPT    32          // elements per thread; TPB*EPT == LEN
#define NP     (EPT/2)     // float2 pairs per thread

typedef float v2 __attribute__((ext_vector_type(2)));

__device__ __forceinline__ v2 vfma(v2 a, v2 b, v2 c) {
    return __builtin_elementwise_fma(a, b, c);   // -> v_pk_fma_f32
}

__device__ __forceinline__ float exp2c(float t) {
    // clamp(exp2(t)) == exp2(min(t,0)); the fmin/fmax pair folds into
    // v_exp_f32's clamp modifier (output clamp to [0,1], +inf -> 1).
    float e = __builtin_amdgcn_exp2f(t);
    return fminf(fmaxf(e, 0.0f), 1.0f);
}

// shifted elu: ep(a) = elu(a)+1, with as = a*log2e prescaled into the weights.
// ep = max(exp2(min(as,0)), 1 + a)  [exp(a) >= 1+a everywhere, equality at 0]
__device__ __forceinline__ float ep_f(float as) {
    const float LN2 = 0.6931471805599453f;
    return fmaxf(exp2c(as), fmaf(as, LN2, 1.0f));
}

__global__ __launch_bounds__(TPB, 8)
void resconv1d_kernel(const float* __restrict__ x_in,
                      const float* __restrict__ w1,
                      const float* __restrict__ b1,
                      const float* __restrict__ w2,
                      const float* __restrict__ b2,
                      float* __restrict__ out)
{
    __shared__ float s_first[2][TPB];
    __shared__ float s_last [2][TPB];
    __shared__ float s_w[NB][6];   // prescaled per-block weights

    const int t   = threadIdx.x;
    const int row = blockIdx.x;

    // ---- load 32 contiguous elements as 16 pairs (8x float4) ----
    const float* xp = x_in + (size_t)row * LEN + (size_t)t * EPT;
    v2 x2[NP];
    #pragma unroll
    for (int k = 0; k < EPT / 4; ++k) {
        float4 v = reinterpret_cast<const float4*>(xp)[k];
        x2[2*k]   = v2{v.x, v.y};
        x2[2*k+1] = v2{v.z, v.w};
    }

    // ---- stage prescaled weights in LDS once ----
    if (t < NB) {
        const float LOG2E = 1.4426950408889634f;
        const float aw20 = 0.9f * w2[2*t];
        const float aw21 = 0.9f * w2[2*t+1];
        s_w[t][0] = w1[2*t]   * LOG2E;
        s_w[t][1] = w1[2*t+1] * LOG2E;
        s_w[t][2] = b1[t]     * LOG2E;
        s_w[t][3] = aw20;
        s_w[t][4] = aw21;
        s_w[t][5] = 0.9f * b2[t] - aw20 - aw21;  // cc
    }

    // loop-invariant halo addressing / edge masks
    const int   idxl  = (t > 0)       ? t - 1 : 0;
    const int   idxr  = (t < TPB - 1) ? t + 1 : TPB - 1;
    const float maskl = (t > 0)       ? 1.0f : 0.0f;   // row edge: x[-1] = 0
    const float maskr = (t < TPB - 1) ? 1.0f : 0.0f;   // row edge: x[L]  = 0

    #pragma unroll 1
    for (int it = 0; it < NB; ++it) {
        const int buf = it & 1;
        s_first[buf][t] = x2[0].x;
        s_last [buf][t] = x2[NP-1].y;
        __syncthreads();   // also covers the one-time s_w writes (it==0)

        const float w10s = s_w[it][0];
        const float w11s = s_w[it][1];
        const float b1s  = s_w[it][2];
        const float aw20 = s_w[it][3];
        const float aw21 = s_w[it][4];
        const float cc   = s_w[it][5];

        const v2 w10v  = {w10s, w10s};
        const v2 w11v  = {w11s, w11s};
        const v2 b1v   = {b1s,  b1s };
        const v2 aw20v = {aw20, aw20};
        const v2 aw21v = {aw21, aw21};
        const v2 ccv   = {cc,   cc  };

        const float xl = s_last [buf][idxl] * maskl;
        const float xr = s_first[buf][idxr] * maskr;

        // prologue: ep pair 0  (as[i] = w10*x[i-1] + w11*x[i] + b1, scaled)
        v2 xm0 = {xl, x2[0].x};
        v2 as0 = vfma(w10v, xm0, vfma(w11v, x2[0], b1v));
        v2 epc = {ep_f(as0.x), ep_f(as0.y)};

        #pragma unroll
        for (int k = 0; k < NP - 1; ++k) {
            // next pair's pre-activations
            v2 xm  = {x2[k].y, x2[k+1].x};
            v2 as1 = vfma(w10v, xm, vfma(w11v, x2[k+1], b1v));
            v2 epn = {ep_f(as1.x), ep_f(as1.y)};
            // combine pair k: out = x + cc + aw20*ep[j] + aw21*ep[j+1]
            v2 ep1 = {epc.y, epn.x};
            x2[k] = vfma(aw20v, epc, vfma(aw21v, ep1, x2[k] + ccv));
            epc = epn;
        }
        // last pair: ep[32] needs xr
        float as32 = fmaf(w10s, x2[NP-1].y, fmaf(w11s, xr, b1s));
        float ep32 = ep_f(as32);
        v2 ep1l = {epc.y, ep32};
        x2[NP-1] = vfma(aw20v, epc, vfma(aw21v, ep1l, x2[NP-1] + ccv));
        // next iteration writes the other halo buffer; one barrier/iter is safe
    }

    // ---- store (8x float4) ----
    float* op = out + (size_t)row * LEN + (size_t)t * EPT;
    #pragma unroll
    for (int k = 0; k < EPT / 4; ++k) {
        float4 v = make_float4(x2[2*k].x, x2[2*k].y, x2[2*k+1].x, x2[2*k+1].y);
        reinterpret_cast<float4*>(op)[k] = v;
    }
}

extern "C" void kernel_launch(void* const* d_in, const int* in_sizes, int n_in,
                              void* d_out, int out_size, void* d_ws, size_t ws_size,
                              hipStream_t stream) {
    const float* x  = (const float*)d_in[0];
    const float* w1 = (const float*)d_in[1];
    const float* b1 = (const float*)d_in[2];
    const float* w2 = (const float*)d_in[3];
    const float* b2 = (const float*)d_in[4];
    float* out = (float*)d_out;

    resconv1d_kernel<<<dim3(BATCH), dim3(TPB), 0, stream>>>(x, w1, b1, w2, b2, out);
}